// Round 5
// baseline (233.946 us; speedup 1.0000x reference)
//
#include <hip/hip_runtime.h>

typedef __attribute__((ext_vector_type(8))) _Float16 f16x8;
typedef __attribute__((ext_vector_type(4))) float f32x4;

#define B_SZ   16
#define N_SEQ  4096
#define M_CTX  77
#define M_PAD  96
#define NH     8

__device__ __forceinline__ _Float16 f2h(float x) { return (_Float16)x; }

// async global->LDS, 16B per lane. dst = wave-uniform base; HW writes
// dst + lane*16. Source address is per-lane (pre-swizzled by caller).
__device__ __forceinline__ void gload16(const void* g, void* l) {
    __builtin_amdgcn_global_load_lds(
        (const __attribute__((address_space(1))) unsigned int*)g,
        (__attribute__((address_space(3))) unsigned int*)l, 16, 0, 0);
}

// ---- DPP 16-lane butterfly reductions (XOR masks {1,2,7,15} span 0..15) ----
template<int C>
__device__ __forceinline__ float dppf(float x) {
    union { float f; int i; } u, v;
    u.f = x;
    v.i = __builtin_amdgcn_mov_dpp(u.i, C, 0xF, 0xF, true);
    return v.f;
}
__device__ __forceinline__ float rmax16(float x) {
    x = fmaxf(x, dppf<0xB1>(x));    // quad_perm(1,0,3,2)  xor 1
    x = fmaxf(x, dppf<0x4E>(x));    // quad_perm(2,3,0,1)  xor 2
    x = fmaxf(x, dppf<0x141>(x));   // row_half_mirror     xor 7
    x = fmaxf(x, dppf<0x140>(x));   // row_mirror          xor 15
    return x;
}
__device__ __forceinline__ float rsum16(float x) {
    x += dppf<0xB1>(x);
    x += dppf<0x4E>(x);
    x += dppf<0x141>(x);
    x += dppf<0x140>(x);
    return x;
}

// ---------------------------------------------------------------------------
// prep: W [K][512] fp32 -> WT [512][K] f16 (LDS-tiled transpose).
// Wq gets the 1/sqrt(D_HEAD)=0.125 softmax scale folded in.
// ---------------------------------------------------------------------------
__global__ __launch_bounds__(256)
void prep(const float* __restrict__ Wq, const float* __restrict__ Wk,
          const float* __restrict__ Wv, const float* __restrict__ Wo,
          _Float16* __restrict__ WqT, _Float16* __restrict__ WkT,
          _Float16* __restrict__ WvT, _Float16* __restrict__ WoT)
{
    __shared__ float t[32][33];
    const float* W; _Float16* WT; int K; float scale = 1.0f;
    switch (blockIdx.z) {
        case 0:  W = Wq; WT = WqT; K = 512; scale = 0.125f; break;
        case 1:  W = Wk; WT = WkT; K = 768; break;
        case 2:  W = Wv; WT = WvT; K = 768; break;
        default: W = Wo; WT = WoT; K = 512; break;
    }
    const int ky = blockIdx.y;
    if (ky * 32 >= K) return;
    const int nx = blockIdx.x;
    const int tr = threadIdx.x >> 5, tc = threadIdx.x & 31;
#pragma unroll
    for (int i = 0; i < 4; ++i) {
        int kr = tr + i * 8;
        t[kr][tc] = W[(size_t)(ky * 32 + kr) * 512 + nx * 32 + tc];
    }
    __syncthreads();
#pragma unroll
    for (int i = 0; i < 4; ++i) {
        int nr = tr + i * 8;
        WT[(size_t)(nx * 32 + nr) * K + ky * 32 + tc] = f2h(t[tc][nr] * scale);
    }
}

// ---------------------------------------------------------------------------
// kv_proj: writes K and V in BANK-SWIZZLED global layouts:
//   Kswz[bh][m][ ((d>>3)^(m&7))*8 + (d&7) ]   m in 0..95 (zeros >= 77)
//   Vswz[bh][d][ ((m>>3)^(d&7))*8 + (m&7) ]   rows of 128 f16 (slots 0..11 used)
// attn reads fragments straight from these with the XOR folded into the addr.
// grid (8 h, 16 b, 2 kv); block 256 = 4 waves
// ---------------------------------------------------------------------------
__global__ __launch_bounds__(256)
void kv_proj(const float* __restrict__ cond, const _Float16* __restrict__ WkT,
             const _Float16* __restrict__ WvT, _Float16* __restrict__ Kswz,
             _Float16* __restrict__ Vswz)
{
    const int tid = threadIdx.x;
    const int l = tid & 63, w = tid >> 6;
    const int lrow = l & 15, lk = l >> 4;
    const int h = blockIdx.x, b = blockIdx.y, which = blockIdx.z;
    const _Float16* WT = which ? WvT : WkT;
    const float* cb = cond + (size_t)b * M_CTX * 768;

    f32x4 acc[5];
#pragma unroll
    for (int i = 0; i < 5; ++i)
#pragma unroll
        for (int e = 0; e < 4; ++e) acc[i][e] = 0.f;

    const int n = h * 64 + w * 16 + lrow;
    for (int kk = 0; kk < 24; ++kk) {
        f16x8 bfrag = *(const f16x8*)(WT + (size_t)n * 768 + kk * 32 + lk * 8);
#pragma unroll
        for (int rt = 0; rt < 5; ++rt) {
            int m = rt * 16 + lrow;
            f16x8 afrag;
#pragma unroll
            for (int j = 0; j < 8; ++j) afrag[j] = (_Float16)0.f;
            if (m < M_CTX) {
                const float* a = cb + (size_t)m * 768 + kk * 32 + lk * 8;
                float4 f0 = *(const float4*)a;
                float4 f1 = *(const float4*)(a + 4);
                afrag[0] = f2h(f0.x); afrag[1] = f2h(f0.y);
                afrag[2] = f2h(f0.z); afrag[3] = f2h(f0.w);
                afrag[4] = f2h(f1.x); afrag[5] = f2h(f1.y);
                afrag[6] = f2h(f1.z); afrag[7] = f2h(f1.w);
            }
            acc[rt] = __builtin_amdgcn_mfma_f32_16x16x32_f16(afrag, bfrag, acc[rt], 0, 0, 0);
        }
    }

    const int bh = b * NH + h;
    const int d = w * 16 + lrow;
    const int dhi = d >> 3, dlo = d & 7;
    if (which == 0) {
        _Float16* Kb = Kswz + (size_t)bh * (M_PAD * 64);
#pragma unroll
        for (int rt = 0; rt < 5; ++rt)
#pragma unroll
            for (int r = 0; r < 4; ++r) {
                int m = rt * 16 + lk * 4 + r;
                Kb[m * 64 + ((dhi ^ (m & 7)) * 8) + dlo] = f2h(acc[rt][r]);
            }
#pragma unroll
        for (int r = 0; r < 4; ++r) {
            int m = 80 + lk * 4 + r;
            Kb[m * 64 + ((dhi ^ (m & 7)) * 8) + dlo] = (_Float16)0.f;
        }
    } else {
        _Float16* Vb = Vswz + (size_t)bh * (64 * 128);
#pragma unroll
        for (int rt = 0; rt < 5; ++rt)
#pragma unroll
            for (int r = 0; r < 4; ++r) {
                int m = rt * 16 + lk * 4 + r;
                Vb[d * 128 + (((m >> 3) ^ dlo) * 8) + (m & 7)] = f2h(acc[rt][r]);
            }
#pragma unroll
        for (int r = 0; r < 4; ++r) {
            int m = 80 + lk * 4 + r;
            Vb[d * 128 + (((m >> 3) ^ dlo) * 8) + (m & 7)] = (_Float16)0.f;
        }
    }
}

// ---------------------------------------------------------------------------
// gemm_q: Qf[65536][512] f16 = x(fp32)[65536][512] @ WqT (scale pre-folded).
// Fused fp32->f16 conversion: A staged as RAW FP32 via global_load_lds
// (pre-swizzled source, zero staging VALU); fragment read = 2x ds_read_b128
// f32 + 8 scalar cvts. B path identical to the proven R2/R3 gemm512.
// 128x128 tile, BK=64, 4 waves; LDS 48KB. XCD-chunked swizzle (2048 = 8*256).
// ---------------------------------------------------------------------------
__global__ __launch_bounds__(256)
void gemm_q(const float* __restrict__ X, const _Float16* __restrict__ BT,
            _Float16* __restrict__ C)
{
    __shared__ float    As[128 * 64];    // 32 KB, row=256B=16 slots of 16B
    __shared__ _Float16 Bs[128 * 64];    // 16 KB

    const int bid = blockIdx.x;
    const int wg = (bid & 7) * 256 + (bid >> 3);
    const int rb = wg >> 2, cb = wg & 3;
    const size_t row0 = (size_t)rb * 128;
    const int col0 = cb * 128;

    const int tid = threadIdx.x;
    const int l = tid & 63, w = tid >> 6;
    const int wy = w >> 1, wx = w & 1;
    const int lrow = l & 15, lk = l >> 4;

    f32x4 acc[4][4];
#pragma unroll
    for (int i = 0; i < 4; ++i)
#pragma unroll
        for (int j = 0; j < 4; ++j)
#pragma unroll
            for (int e = 0; e < 4; ++e) acc[i][j][e] = 0.f;

    // A staging: inst i covers rows w*32+i*4 .. +4; lane -> row i*4+(l>>4),
    // slot16 (l&15); src col-slot pre-XORed with (row&7) = (i*4 + l>>4)&7.
    const int r4 = l >> 4;
    const int sA0 = (l & 15) ^ r4;           // even i
    const int sA1 = (l & 15) ^ (4 + r4);     // odd i
    const float* xa0 = X + (row0 + w * 32 + r4) * 512 + sA0 * 4;
    const float* xa1 = X + (row0 + w * 32 + r4) * 512 + sA1 * 4;
    // B staging: lane -> row l>>3 within 8-row groups, slot8 (l&7)^(row&7)
    const int srow8 = l >> 3;
    const int sB = (l & 7) ^ (srow8 & 7);
    const _Float16* bsrc = BT + (size_t)(col0 + w * 32 + srow8) * 512 + sB * 8;

    for (int kt = 0; kt < 8; ++kt) {
#pragma unroll
        for (int i = 0; i < 8; ++i) {
            const float* s = (i & 1 ? xa1 : xa0) + (size_t)i * 4 * 512 + kt * 64;
            gload16(s, (char*)As + ((w * 8 + i) * 1024));
        }
#pragma unroll
        for (int s4 = 0; s4 < 4; ++s4)
            gload16(bsrc + (size_t)s4 * 8 * 512 + kt * 64, (char*)Bs + ((w * 4 + s4) * 1024));
        __syncthreads();   // drains vmcnt: tiles resident

#pragma unroll
        for (int kk = 0; kk < 2; ++kk) {
            f16x8 af[4], bf[4];
#pragma unroll
            for (int mt = 0; mt < 4; ++mt) {
                int q = wy * 64 + mt * 16 + lrow;
                int sb = kk * 8 + lk * 2, sw = lrow & 7;
                f32x4 p0 = *(const f32x4*)&As[q * 64 + ((sb ^ sw) * 4)];
                f32x4 p1 = *(const f32x4*)&As[q * 64 + (((sb + 1) ^ sw) * 4)];
                f16x8 a;
                a[0] = f2h(p0[0]); a[1] = f2h(p0[1]); a[2] = f2h(p0[2]); a[3] = f2h(p0[3]);
                a[4] = f2h(p1[0]); a[5] = f2h(p1[1]); a[6] = f2h(p1[2]); a[7] = f2h(p1[3]);
                af[mt] = a;
            }
#pragma unroll
            for (int nt = 0; nt < 4; ++nt) {
                int R = wx * 64 + nt * 16 + lrow;
                int p = (kk * 4 + lk) ^ (lrow & 7);
                bf[nt] = *(const f16x8*)&Bs[R * 64 + p * 8];
            }
#pragma unroll
            for (int mt = 0; mt < 4; ++mt)
#pragma unroll
                for (int nt = 0; nt < 4; ++nt)
                    acc[mt][nt] = __builtin_amdgcn_mfma_f32_16x16x32_f16(af[mt], bf[nt], acc[mt][nt], 0, 0, 0);
        }
        __syncthreads();   // protect LDS before next stage
    }

#pragma unroll
    for (int mt = 0; mt < 4; ++mt)
#pragma unroll
        for (int nt = 0; nt < 4; ++nt)
#pragma unroll
            for (int r = 0; r < 4; ++r) {
                size_t row = row0 + wy * 64 + mt * 16 + lk * 4 + r;
                int col = col0 + wx * 64 + nt * 16 + lrow;
                C[row * 512 + col] = f2h(acc[mt][nt][r]);
            }
}

// ---------------------------------------------------------------------------
// attn_oproj: fused attention + O-projection. Block = (b, 128 rows), 8 waves.
// Per head h: wave w runs attn for m-tile w (16 q-rows): QK^T (K frags from
// L2-hot Kswz), DPP softmax (deferred 1/sum), PV (V frags from Vswz), writes
// normalized AO_h into XOR-swizzled LDS [128][64] (dbuf on h&1); one
// __syncthreads; then out[:,64w..] += AO_h @ Wo_h (K=64) into persistent
// acc[8][4]. Race-free: write(h+1)->buf p^1 and read(h-1)->buf p^1 are
// separated by sync(h). Epilogue adds bias, writes fp32.
// grid (32 chunks, 16 b); block 512.
// ---------------------------------------------------------------------------
__global__ __launch_bounds__(512)
void attn_oproj(const _Float16* __restrict__ Q, const _Float16* __restrict__ Kswz,
                const _Float16* __restrict__ Vswz, const _Float16* __restrict__ WoT,
                const float* __restrict__ bo, float* __restrict__ out)
{
    __shared__ _Float16 AO2[2][128 * 64];   // 32 KB (dbuf, XOR-swizzled rows)
    __shared__ _Float16 Pl[8][16][104];     // 26 KB per-wave P tiles

    const int tid = threadIdx.x;
    const int l = tid & 63, w = tid >> 6;
    const int lrow = l & 15, lk = l >> 4;
    const int chunk = blockIdx.x, b = blockIdx.y;
    const size_t rowbase = (size_t)b * N_SEQ + chunk * 128;

    f32x4 acc[8][4];   // out: rows mt*16+lk*4+r, cols w*64+nt*16+lrow
#pragma unroll
    for (int i = 0; i < 8; ++i)
#pragma unroll
        for (int j = 0; j < 4; ++j)
#pragma unroll
            for (int e = 0; e < 4; ++e) acc[i][j][e] = 0.f;

    // zero P pad cols 80..95 once (96..103 never read)
    for (int idx = l; idx < 256; idx += 64)
        Pl[w][idx >> 4][80 + (idx & 15)] = (_Float16)0.f;

    const bool m4ok = (lrow < 13);

    for (int h = 0; h < NH; ++h) {
        const int bh = b * NH + h;

        // ---- Q frags: this wave's m-tile = rows w*16 .. w*16+15 ----
        const _Float16* Qb = Q + (rowbase + w * 16 + lrow) * 512 + h * 64;
        f16x8 qf0 = *(const f16x8*)(Qb + lk * 8);
        f16x8 qf1 = *(const f16x8*)(Qb + 32 + lk * 8);

        // ---- S = Q K^T (K frags direct from swizzled global, L2-hot) ----
        const _Float16* Kb = Kswz + (size_t)bh * (M_PAD * 64);
        f32x4 s[5];
#pragma unroll
        for (int i = 0; i < 5; ++i)
#pragma unroll
            for (int e = 0; e < 4; ++e) s[i][e] = 0.f;
#pragma unroll
        for (int ct = 0; ct < 5; ++ct) {
            int m = ct * 16 + lrow;
            f16x8 k0 = *(const f16x8*)(Kb + m * 64 + ((lk ^ (m & 7)) * 8));
            f16x8 k1 = *(const f16x8*)(Kb + m * 64 + (((4 + lk) ^ (m & 7)) * 8));
            s[ct] = __builtin_amdgcn_mfma_f32_16x16x32_f16(qf0, k0, s[ct], 0, 0, 0);
            s[ct] = __builtin_amdgcn_mfma_f32_16x16x32_f16(qf1, k1, s[ct], 0, 0, 0);
        }

        // ---- softmax: DPP butterfly over the 16 lrow lanes ----
        float rinv[4];
#pragma unroll
        for (int r = 0; r < 4; ++r) {
            float v0 = s[0][r], v1 = s[1][r], v2 = s[2][r], v3 = s[3][r], v4 = s[4][r];
            float mx = fmaxf(fmaxf(v0, v1), fmaxf(v2, v3));
            mx = fmaxf(mx, m4ok ? v4 : -1e30f);
            mx = rmax16(mx);
            float e0 = __expf(v0 - mx), e1 = __expf(v1 - mx);
            float e2 = __expf(v2 - mx), e3 = __expf(v3 - mx);
            float e4 = m4ok ? __expf(v4 - mx) : 0.f;
            float sum = ((e0 + e1) + (e2 + e3)) + e4;
            sum = rsum16(sum);
            rinv[r] = 1.0f / sum;
            int prow = lk * 4 + r;
            Pl[w][prow][lrow]      = f2h(e0);
            Pl[w][prow][16 + lrow] = f2h(e1);
            Pl[w][prow][32 + lrow] = f2h(e2);
            Pl[w][prow][48 + lrow] = f2h(e3);
            Pl[w][prow][64 + lrow] = f2h(e4);
        }

        // ---- O = P V (V frags direct from swizzled global) ----
        const _Float16* Vb = Vswz + (size_t)bh * (64 * 128);
        f32x4 o[4];
#pragma unroll
        for (int i = 0; i < 4; ++i)
#pragma unroll
            for (int e2 = 0; e2 < 4; ++e2) o[i][e2] = 0.f;
#pragma unroll
        for (int kk = 0; kk < 3; ++kk) {
            f16x8 pa = *(const f16x8*)&Pl[w][lrow][kk * 32 + lk * 8];
#pragma unroll
            for (int ctd = 0; ctd < 4; ++ctd) {
                int d = ctd * 16 + lrow;
                f16x8 vf = *(const f16x8*)(Vb + d * 128 + (((kk * 4 + lk) ^ (d & 7)) * 8));
                o[ctd] = __builtin_amdgcn_mfma_f32_16x16x32_f16(pa, vf, o[ctd], 0, 0, 0);
            }
        }

        // ---- AO_h -> LDS (normalized, row-XOR-swizzled) ----
        _Float16* A0 = AO2[h & 1];
#pragma unroll
        for (int ctd = 0; ctd < 4; ++ctd)
#pragma unroll
            for (int r = 0; r < 4; ++r) {
                int q = w * 16 + lk * 4 + r;
                int col = ctd * 16 + lrow;
                A0[q * 64 + (((col >> 3) ^ (q & 7)) * 8) + (col & 7)] =
                    f2h(o[ctd][r] * rinv[r]);
            }
        __syncthreads();   // AO_h complete & visible

        // ---- out += AO_h @ Wo_h (K = 64) ----
        const _Float16* Wb = WoT + h * 64;
#pragma unroll
        for (int kk = 0; kk < 2; ++kk) {
            f16x8 bf[4];
#pragma unroll
            for (int nt = 0; nt < 4; ++nt)
                bf[nt] = *(const f16x8*)(Wb + (size_t)(w * 64 + nt * 16 + lrow) * 512 + kk * 32 + lk * 8);
#pragma unroll
            for (int mt = 0; mt < 8; ++mt) {
                int q = mt * 16 + lrow;
                f16x8 a = *(const f16x8*)&A0[q * 64 + (((kk * 4 + lk) ^ (lrow & 7)) * 8)];
#pragma unroll
                for (int nt = 0; nt < 4; ++nt)
                    acc[mt][nt] = __builtin_amdgcn_mfma_f32_16x16x32_f16(a, bf[nt], acc[mt][nt], 0, 0, 0);
            }
        }
        // no trailing barrier needed: next head writes the OTHER AO buffer,
        // whose last readers finished before THIS head's __syncthreads.
    }

    // ---- epilogue: bias + fp32 store ----
#pragma unroll
    for (int mt = 0; mt < 8; ++mt)
#pragma unroll
        for (int nt = 0; nt < 4; ++nt)
#pragma unroll
            for (int r = 0; r < 4; ++r) {
                size_t row = rowbase + mt * 16 + lk * 4 + r;
                int col = w * 64 + nt * 16 + lrow;
                out[row * 512 + col] = acc[mt][nt][r] + bo[col];
            }
}

// ---------------------------------------------------------------------------
extern "C" void kernel_launch(void* const* d_in, const int* in_sizes, int n_in,
                              void* d_out, int out_size, void* d_ws, size_t ws_size,
                              hipStream_t stream)
{
    (void)in_sizes; (void)n_in; (void)out_size; (void)ws_size;
    const float* x    = (const float*)d_in[0];
    const float* cond = (const float*)d_in[1];
    const float* Wq   = (const float*)d_in[2];
    const float* Wk   = (const float*)d_in[3];
    const float* Wv   = (const float*)d_in[4];
    const float* Wo   = (const float*)d_in[5];
    const float* bo   = (const float*)d_in[6];

    char* ws = (char*)d_ws;
    _Float16* WqT  = (_Float16*)(ws);                        // 524288
    _Float16* WoT  = (_Float16*)(ws + 524288);               // 524288
    _Float16* Kswz = (_Float16*)(ws + 1048576);              // 1572864
    _Float16* Vswz = (_Float16*)(ws + 2621440);              // 2097152
    _Float16* Qf   = (_Float16*)(ws + 4718592);              // 67108864
    // WkT/WvT alias Qf's head: consumed by kv_proj BEFORE gemm_q writes Qf
    _Float16* WkT  = (_Float16*)(ws + 4718592);              // 786432
    _Float16* WvT  = (_Float16*)(ws + 4718592 + 786432);     // 786432
    // total ws: 71,827,456 bytes (same as previous rounds)

    prep<<<dim3(16, 24, 4), 256, 0, stream>>>(Wq, Wk, Wv, Wo, WqT, WkT, WvT, WoT);
    kv_proj<<<dim3(8, 16, 2), 256, 0, stream>>>(cond, WkT, WvT, Kswz, Vswz);
    gemm_q<<<dim3(2048), 256, 0, stream>>>(x, WqT, Qf);
    attn_oproj<<<dim3(32, 16), 512, 0, stream>>>(Qf, Kswz, Vswz, WoT, bo, (float*)d_out);
}